// Round 3
// baseline (446.096 us; speedup 1.0000x reference)
//
#include <hip/hip_runtime.h>
#include <hip/hip_bf16.h>

#define NB   8
#define CCH  256
#define KCH  128
#define SSP  4096

typedef unsigned short u16;
typedef __attribute__((ext_vector_type(8))) short  bfrag;  // 8 bf16 = 4 VGPRs
typedef __attribute__((ext_vector_type(4))) float  ffrag;  // 4 fp32 acc

#define MFMA16(a, b, c) __builtin_amdgcn_mfma_f32_16x16x32_bf16((a), (b), (c), 0, 0, 0)
// u16-index XOR swizzle: flips bits 3-5 (16B granule) by row&7 -> bank spread
#define SWZ(i, r) ((unsigned)(i) ^ ((((unsigned)(r)) & 7u) << 3))

__device__ __forceinline__ u16 f2b(float f) {            // fp32 -> bf16 RNE
    union { float f; unsigned u; } v; v.f = f;
    return (u16)((v.u + 0x7fffu + ((v.u >> 16) & 1u)) >> 16);
}

__device__ __forceinline__ unsigned cvt_pk_bf16(float lo, float hi) {
    unsigned r;
    asm("v_cvt_pk_bf16_f32 %0, %1, %2" : "=v"(r) : "v"(lo), "v"(hi));
    return r;
}

// ---------------------------------------------------------------------------
// K1: g and phi projections, MFMA, register-pipelined staging. (unchanged)
// ---------------------------------------------------------------------------
__global__ __launch_bounds__(256, 2) void proj_gp_kernel(
    const float* __restrict__ x,
    const float* __restrict__ Wg, const float* __restrict__ bg,
    const float* __restrict__ Wp, const float* __restrict__ bp,
    u16* __restrict__ G,   // [N,K,S] transposed
    u16* __restrict__ P)   // [N,S,K]
{
    __shared__ __align__(16) u16 sm[12800];
    const int tid  = threadIdx.x;
    const int wv   = tid >> 6;
    const int lane = tid & 63;
    const int quad = lane >> 4, l16 = lane & 15;
    const int bid  = blockIdx.x;
    const int n  = bid & 7;
    const int s0 = (bid >> 3) * 64;

    const ffrag zf = {0.f, 0.f, 0.f, 0.f};
    ffrag ga[8], pa[8];
#pragma unroll
    for (int kb = 0; kb < 8; kb++) { ga[kb] = zf; pa[kb] = zf; }

    float4 xreg[2], wgreg[4], wpreg[4];
#pragma unroll
    for (int i = 0; i < 2; i++) {
        int f = tid + i * 256;
        int c = f >> 4, s4 = (f & 15) * 4;
        xreg[i] = *(const float4*)&x[((size_t)n * CCH + c) * SSP + s0 + s4];
    }
#pragma unroll
    for (int i = 0; i < 4; i++) {
        int f = tid + i * 256;
        int k = f >> 3, co = (f & 7) * 4;
        wgreg[i] = *(const float4*)&Wg[k * CCH + co];
        wpreg[i] = *(const float4*)&Wp[k * CCH + co];
    }

    for (int c0 = 0; c0 < CCH; c0 += 32) {
        __syncthreads();
#pragma unroll
        for (int i = 0; i < 2; i++) {
            int f = tid + i * 256;
            int c = f >> 4, s4 = (f & 15) * 4;
            sm[(s4 + 0) * 40 + c] = f2b(xreg[i].x);
            sm[(s4 + 1) * 40 + c] = f2b(xreg[i].y);
            sm[(s4 + 2) * 40 + c] = f2b(xreg[i].z);
            sm[(s4 + 3) * 40 + c] = f2b(xreg[i].w);
        }
#pragma unroll
        for (int i = 0; i < 4; i++) {
            int f = tid + i * 256;
            int k = f >> 3, co = (f & 7) * 4;
            ushort4 g4 = {f2b(wgreg[i].x), f2b(wgreg[i].y), f2b(wgreg[i].z), f2b(wgreg[i].w)};
            ushort4 p4 = {f2b(wpreg[i].x), f2b(wpreg[i].y), f2b(wpreg[i].z), f2b(wpreg[i].w)};
            *(ushort4*)&sm[2560 + k * 40 + co] = g4;
            *(ushort4*)&sm[7680 + k * 40 + co] = p4;
        }
        if (c0 + 32 < CCH) {
#pragma unroll
            for (int i = 0; i < 2; i++) {
                int f = tid + i * 256;
                int c = f >> 4, s4 = (f & 15) * 4;
                xreg[i] = *(const float4*)&x[((size_t)n * CCH + c0 + 32 + c) * SSP + s0 + s4];
            }
#pragma unroll
            for (int i = 0; i < 4; i++) {
                int f = tid + i * 256;
                int k = f >> 3, co = (f & 7) * 4;
                wgreg[i] = *(const float4*)&Wg[k * CCH + c0 + 32 + co];
                wpreg[i] = *(const float4*)&Wp[k * CCH + c0 + 32 + co];
            }
        }
        __syncthreads();
        bfrag a = *(const bfrag*)&sm[(16 * wv + l16) * 40 + quad * 8];
#pragma unroll
        for (int kb = 0; kb < 8; kb++) {
            bfrag bgf = *(const bfrag*)&sm[2560 + (16 * kb + l16) * 40 + quad * 8];
            bfrag bpf = *(const bfrag*)&sm[7680 + (16 * kb + l16) * 40 + quad * 8];
            ga[kb] = MFMA16(a, bgf, ga[kb]);
            pa[kb] = MFMA16(a, bpf, pa[kb]);
        }
    }
#pragma unroll
    for (int kb = 0; kb < 8; kb++) {
        int k = l16 + 16 * kb;
        float bgv = bg[k], bpv = bp[k];
        int srow = s0 + 16 * wv + quad * 4;
        ushort4 g4 = {f2b(ga[kb][0] + bgv), f2b(ga[kb][1] + bgv),
                      f2b(ga[kb][2] + bgv), f2b(ga[kb][3] + bgv)};
        *(ushort4*)&G[(size_t)n * KCH * SSP + (size_t)k * SSP + srow] = g4;
#pragma unroll
        for (int r = 0; r < 4; r++)
            P[((size_t)n * SSP + srow + r) * KCH + k] = f2b(pa[kb][r] + bpv);
    }
}

// ---------------------------------------------------------------------------
// K2: fused theta-proj + flash attention + out-proj, all MFMA.
// Round-8 changes vs round 7 (conflict source = PS scalar stores; barrier
// lockstep at 1 block/CU):
//  - SWAPPED QK^T: sa = MFMA(K_frag, Q_frag) -> lane holds P[t][q=l16].
//    Softmax fully in-register: exp2 -> v_cvt_pk_bf16_f32 -> 16 __shfl
//    (ds_bpermute) quad-redistribution builds the PV A-frag. PS LDS gone,
//    no scalar LDS stores in t-loop, no lgkm drain before PV.
//  - l: single per-lane accumulator; 2 shfl_xor reduce AFTER the loop.
//  - 256-thread blocks, q-tile 64, grid 512 = 2 INDEPENDENT blocks/CU:
//    barrier/vmcnt drains of one block overlap compute of the other.
//  - LDS 48 KB declared: QS/YS@0 (16KB) | ph0 XT@8192 WT@10752 |
//    t-loop KS@8192 GT@16384 | epi WO@8192 (Wo staged in 64-row quarters).
// ---------------------------------------------------------------------------
__global__ __launch_bounds__(256, 2) void attn_fused_kernel(
    const float* __restrict__ x,
    const float* __restrict__ Wt, const float* __restrict__ bt,
    const u16* __restrict__ Pb,   // phi rows bf16 [N,S,K]
    const u16* __restrict__ Gt,   // g bf16 TRANSPOSED [N,K,S]
    const float* __restrict__ Wo, const float* __restrict__ bo,
    float* __restrict__ out)
{
    __shared__ __align__(16) u16 sm[24576];     // 48 KB
    const int tid  = threadIdx.x;
    const int wv   = tid >> 6;                  // 0..3
    const int lane = tid & 63;
    const int quad = lane >> 4, l16 = lane & 15;
    const int bid  = blockIdx.x;
    const int n    = bid & 7;
    const int q0   = (bid >> 3) * 64;
    // 1/sqrt(128) * log2(e): exp(s*scale) == exp2(s*qscale)
    const float qscale = 0.08838834764831845f * 1.4426950408889634f;
    const ffrag zf = {0.f, 0.f, 0.f, 0.f};

    const int XTb = 8192, WTb = 10752, KSb = 8192, GTb = 16384, WOb = 8192;

    const u16* Pbase = Pb + (size_t)n * SSP * KCH;
    const u16* Gbase = Gt + (size_t)n * KCH * SSP;

    // ---- issue first K/G tile loads NOW; they complete during phase 0 ----
    uint4 kreg[4], greg[4];
#pragma unroll
    for (int i = 0; i < 4; i++) {
        int f = tid + i * 256;
        int row = f >> 4, c8 = (f & 15) * 8;
        kreg[i] = *(const uint4*)(Pbase + (size_t)row * KCH + c8);
    }
#pragma unroll
    for (int i = 0; i < 4; i++) {
        int f = tid + i * 256;
        int k = f >> 3, ch = f & 7;
        greg[i] = *(const uint4*)(Gbase + (size_t)k * SSP + ch * 8);
    }

    // ---------------- Phase 0: Qs = (theta(x)+bt)*qscale, bf16 ----------------
    {
        ffrag qa[8];
#pragma unroll
        for (int kb = 0; kb < 8; kb++) qa[kb] = zf;

        for (int c0 = 0; c0 < CCH; c0 += 32) {
#pragma unroll
            for (int i = 0; i < 2; i++) {
                int f = tid + i * 256;
                int c = f >> 4, s4 = (f & 15) * 4;
                float4 xv = *(const float4*)&x[((size_t)n * CCH + c0 + c) * SSP + q0 + s4];
                sm[XTb + (s4 + 0) * 40 + c] = f2b(xv.x);
                sm[XTb + (s4 + 1) * 40 + c] = f2b(xv.y);
                sm[XTb + (s4 + 2) * 40 + c] = f2b(xv.z);
                sm[XTb + (s4 + 3) * 40 + c] = f2b(xv.w);
            }
#pragma unroll
            for (int i = 0; i < 4; i++) {
                int f = tid + i * 256;
                int k = f >> 3, co = (f & 7) * 4;
                float4 wq4 = *(const float4*)&Wt[k * CCH + c0 + co];
                ushort4 q4 = {f2b(wq4.x), f2b(wq4.y), f2b(wq4.z), f2b(wq4.w)};
                *(ushort4*)&sm[WTb + k * 40 + co] = q4;
            }
            __syncthreads();
            bfrag aq = *(const bfrag*)&sm[XTb + (16 * wv + l16) * 40 + quad * 8];
#pragma unroll
            for (int kb = 0; kb < 8; kb++) {
                bfrag bw = *(const bfrag*)&sm[WTb + (16 * kb + l16) * 40 + quad * 8];
                qa[kb] = MFMA16(aq, bw, qa[kb]);
            }
            __syncthreads();
        }
#pragma unroll
        for (int kb = 0; kb < 8; kb++) {
            float btv = bt[l16 + 16 * kb];
#pragma unroll
            for (int r = 0; r < 4; r++) {
                int row = 16 * wv + quad * 4 + r;
                sm[SWZ(row * 128 + l16 + 16 * kb, row)] = f2b((qa[kb][r] + btv) * qscale);
            }
        }
        // QS rows are wave-private; in-wave LDS ordering suffices below.
    }

    // ---- hoist Q B-fragments (own rows, no barrier needed) ----
    bfrag qf[4];
#pragma unroll
    for (int kc = 0; kc < 4; kc++)
        qf[kc] = *(const bfrag*)&sm[SWZ((16 * wv + l16) * 128 + kc * 32 + quad * 8, l16)];

    // ---------------- Phase 1: flash attention over t-tiles ----------------
    ffrag O[8];
#pragma unroll
    for (int kb = 0; kb < 8; kb++) O[kb] = zf;
    float l_lane = 0.f;
    const bool hi32 = lane >= 32;                       // quad 2,3
    const int srcA = (((2 * quad) & 3) << 4) + l16;     // quads {0,2,0,2}
    const int srcB = (((2 * quad + 1) & 3) << 4) + l16; // quads {1,3,1,3}

    for (int t0 = 0; t0 < SSP; t0 += 64) {
        __syncthreads();                    // previous tile fully consumed
        // ---- commit pipelined tile to LDS (swizzled) ----
#pragma unroll
        for (int i = 0; i < 4; i++) {
            int f = tid + i * 256;
            int row = f >> 4, c8 = (f & 15) * 8;
            *(uint4*)&sm[KSb + SWZ(row * 128 + c8, row)] = kreg[i];
        }
#pragma unroll
        for (int i = 0; i < 4; i++) {
            int f = tid + i * 256;
            int k = f >> 3, ch = f & 7;
            *(uint4*)&sm[GTb + SWZ(k * 64 + ch * 8, k)] = greg[i];
        }
        // ---- prefetch next tile (in flight across the whole compute) ----
        if (t0 + 64 < SSP) {
#pragma unroll
            for (int i = 0; i < 4; i++) {
                int f = tid + i * 256;
                int row = f >> 4, c8 = (f & 15) * 8;
                kreg[i] = *(const uint4*)(Pbase + (size_t)(t0 + 64 + row) * KCH + c8);
            }
#pragma unroll
            for (int i = 0; i < 4; i++) {
                int f = tid + i * 256;
                int k = f >> 3, ch = f & 7;
                greg[i] = *(const uint4*)(Gbase + (size_t)k * SSP + t0 + 64 + ch * 8);
            }
        }
        __syncthreads();                    // staging visible

        // ---- QK^T SWAPPED: sa[tb] lane holds S[t=16tb+quad*4+r][q=l16] ----
        ffrag sa[4];
#pragma unroll
        for (int tb = 0; tb < 4; tb++) sa[tb] = zf;
#pragma unroll
        for (int kc = 0; kc < 4; kc++)
#pragma unroll
            for (int tb = 0; tb < 4; tb++) {
                bfrag bk = *(const bfrag*)&sm[KSb + SWZ((16 * tb + l16) * 128 + kc * 32 + quad * 8, l16)];
                sa[tb] = MFMA16(bk, qf[kc], sa[tb]);
            }

        // ---- softmax numerator in-register: exp2 -> pack bf16 pairs ----
        unsigned pk[4][2];
#pragma unroll
        for (int tb = 0; tb < 4; tb++) {
            float p0 = __builtin_amdgcn_exp2f(sa[tb][0]);
            float p1 = __builtin_amdgcn_exp2f(sa[tb][1]);
            float p2 = __builtin_amdgcn_exp2f(sa[tb][2]);
            float p3 = __builtin_amdgcn_exp2f(sa[tb][3]);
            l_lane += (p0 + p1) + (p2 + p3);
            pk[tb][0] = cvt_pk_bf16(p0, p1);
            pk[tb][1] = cvt_pk_bf16(p2, p3);
        }

        // ---- PV: A-frag built by quad-redistribution (16 shfl, no LDS) ----
        // dest lane (quad,l16), elem j: t = 32*tc + 8*quad + j, sourced from
        // pk[2*tc + (quad>>1)][(j&3)>>1...] at lane ((2*quad + (j>>2))&3)*16 + l16
#pragma unroll
        for (int tc = 0; tc < 2; tc++) {
            unsigned w0A = __shfl(pk[2 * tc][0],     srcA);
            unsigned w0B = __shfl(pk[2 * tc + 1][0], srcA);
            unsigned w1A = __shfl(pk[2 * tc][1],     srcA);
            unsigned w1B = __shfl(pk[2 * tc + 1][1], srcA);
            unsigned w2A = __shfl(pk[2 * tc][0],     srcB);
            unsigned w2B = __shfl(pk[2 * tc + 1][0], srcB);
            unsigned w3A = __shfl(pk[2 * tc][1],     srcB);
            unsigned w3B = __shfl(pk[2 * tc + 1][1], srcB);
            union { unsigned u[4]; bfrag b; } apu;
            apu.u[0] = hi32 ? w0B : w0A;
            apu.u[1] = hi32 ? w1B : w1A;
            apu.u[2] = hi32 ? w2B : w2A;
            apu.u[3] = hi32 ? w3B : w3A;
#pragma unroll
            for (int kb = 0; kb < 8; kb++) {
                bfrag bg = *(const bfrag*)&sm[GTb + SWZ((16 * kb + l16) * 64 + tc * 32 + quad * 8, l16)];
                O[kb] = MFMA16(apu.b, bg, O[kb]);
            }
        }
    }

    // ---------------- Phase 2: reduce l; y -> YS; out = x + Wo*y + bo ----
    {
        float rs = l_lane;                  // partial for q=l16 over own quad's t
        rs += __shfl_xor(rs, 16);
        rs += __shfl_xor(rs, 32);
        float linv = 1.0f / rs;             // lane holds 1/L[q_local = l16]
        float lr[4];
#pragma unroll
        for (int r = 0; r < 4; r++) lr[r] = __shfl(linv, quad * 4 + r);
#pragma unroll
        for (int kb = 0; kb < 8; kb++)
#pragma unroll
            for (int r = 0; r < 4; r++) {
                int row = 16 * wv + quad * 4 + r;
                sm[SWZ(row * 128 + l16 + 16 * kb, row)] = f2b(O[kb][r] * lr[r]);
            }
    }

#pragma unroll
    for (int qtr = 0; qtr < 4; qtr++) {
        __syncthreads();    // KS/GT (or prev WO) reads done before overwrite
        // stage Wo rows [qtr*64, qtr*64+64) bf16, swizzled [64][128]
#pragma unroll
        for (int i = 0; i < 8; i++) {
            int f = tid + i * 256;
            int c = f >> 5, ko = (f & 31) * 4;
            float4 w = *(const float4*)&Wo[(size_t)(qtr * 64 + c) * KCH + ko];
            ushort4 w4 = {f2b(w.x), f2b(w.y), f2b(w.z), f2b(w.w)};
            *(ushort4*)&sm[WOb + SWZ(c * 128 + ko, c)] = w4;
        }
        __syncthreads();

        ffrag zc[4];
#pragma unroll
        for (int cb = 0; cb < 4; cb++) zc[cb] = zf;
#pragma unroll
        for (int kc = 0; kc < 4; kc++) {
            bfrag ay = *(const bfrag*)&sm[SWZ((16 * wv + l16) * 128 + kc * 32 + quad * 8, l16)];
#pragma unroll
            for (int cb = 0; cb < 4; cb++) {
                bfrag bw = *(const bfrag*)&sm[WOb + SWZ((16 * cb + l16) * 128 + kc * 32 + quad * 8, l16)];
                zc[cb] = MFMA16(ay, bw, zc[cb]);
            }
        }
#pragma unroll
        for (int cb = 0; cb < 4; cb++) {
            int c = qtr * 64 + 16 * cb + l16;
            float bc = bo[c];
            size_t base = ((size_t)n * CCH + c) * SSP + q0 + 16 * wv + quad * 4;
            float4 xv = *(const float4*)&x[base];
            float4 ov;
            ov.x = xv.x + zc[cb][0] + bc;
            ov.y = xv.y + zc[cb][1] + bc;
            ov.z = xv.z + zc[cb][2] + bc;
            ov.w = xv.w + zc[cb][3] + bc;
            *(float4*)&out[base] = ov;
        }
    }
}

// ---------------------------------------------------------------------------
extern "C" void kernel_launch(void* const* d_in, const int* in_sizes, int n_in,
                              void* d_out, int out_size, void* d_ws, size_t ws_size,
                              hipStream_t stream) {
    const float* x  = (const float*)d_in[0];
    const float* Wg = (const float*)d_in[1];
    const float* bg = (const float*)d_in[2];
    const float* Wt = (const float*)d_in[3];
    const float* bt = (const float*)d_in[4];
    const float* Wp = (const float*)d_in[5];
    const float* bp = (const float*)d_in[6];
    const float* Wo = (const float*)d_in[7];
    const float* bo = (const float*)d_in[8];
    float* out = (float*)d_out;

    // ws: 16 MB total (verified-safe): G^T bf16 8MB + P bf16 8MB.
    u16* G = (u16*)d_ws;                       // [N,K,S] transposed
    u16* P = G + (size_t)NB * SSP * KCH;       // [N,S,K]

    proj_gp_kernel<<<dim3(NB * SSP / 64), 256, 0, stream>>>(x, Wg, bg, Wp, bp, G, P);
    attn_fused_kernel<<<dim3(NB * SSP / 64), 256, 0, stream>>>(x, Wt, bt, P, G, Wo, bo, out);
}

// Round 4
// 440.429 us; speedup vs baseline: 1.0129x; 1.0129x over previous
//
#include <hip/hip_runtime.h>
#include <hip/hip_bf16.h>

#define NB   8
#define CCH  256
#define KCH  128
#define SSP  4096

typedef unsigned short u16;
typedef __attribute__((ext_vector_type(8))) short  bfrag;  // 8 bf16 = 4 VGPRs
typedef __attribute__((ext_vector_type(4))) float  ffrag;  // 4 fp32 acc
typedef __attribute__((ext_vector_type(4))) unsigned int uint4v;

#define MFMA16(a, b, c) __builtin_amdgcn_mfma_f32_16x16x32_bf16((a), (b), (c), 0, 0, 0)
// u16-index XOR swizzle: flips bits 3-5 (16B granule) by row&7 -> bank spread
#define SWZ(i, r) ((unsigned)(i) ^ ((((unsigned)(r)) & 7u) << 3))

__device__ __forceinline__ u16 f2b(float f) {            // fp32 -> bf16 RNE
    union { float f; unsigned u; } v; v.f = f;
    return (u16)((v.u + 0x7fffu + ((v.u >> 16) & 1u)) >> 16);
}

__device__ __forceinline__ unsigned cvt_pk_bf16(float lo, float hi) {
    unsigned r;
    asm("v_cvt_pk_bf16_f32 %0, %1, %2" : "=v"(r) : "v"(lo), "v"(hi));
    return r;
}

// ---------------------------------------------------------------------------
// K1: g and phi projections, MFMA, register-pipelined staging. (unchanged)
// ---------------------------------------------------------------------------
__global__ __launch_bounds__(256, 2) void proj_gp_kernel(
    const float* __restrict__ x,
    const float* __restrict__ Wg, const float* __restrict__ bg,
    const float* __restrict__ Wp, const float* __restrict__ bp,
    u16* __restrict__ G,   // [N,K,S] transposed
    u16* __restrict__ P)   // [N,S,K]
{
    __shared__ __align__(16) u16 sm[12800];
    const int tid  = threadIdx.x;
    const int wv   = tid >> 6;
    const int lane = tid & 63;
    const int quad = lane >> 4, l16 = lane & 15;
    const int bid  = blockIdx.x;
    const int n  = bid & 7;
    const int s0 = (bid >> 3) * 64;

    const ffrag zf = {0.f, 0.f, 0.f, 0.f};
    ffrag ga[8], pa[8];
#pragma unroll
    for (int kb = 0; kb < 8; kb++) { ga[kb] = zf; pa[kb] = zf; }

    float4 xreg[2], wgreg[4], wpreg[4];
#pragma unroll
    for (int i = 0; i < 2; i++) {
        int f = tid + i * 256;
        int c = f >> 4, s4 = (f & 15) * 4;
        xreg[i] = *(const float4*)&x[((size_t)n * CCH + c) * SSP + s0 + s4];
    }
#pragma unroll
    for (int i = 0; i < 4; i++) {
        int f = tid + i * 256;
        int k = f >> 3, co = (f & 7) * 4;
        wgreg[i] = *(const float4*)&Wg[k * CCH + co];
        wpreg[i] = *(const float4*)&Wp[k * CCH + co];
    }

    for (int c0 = 0; c0 < CCH; c0 += 32) {
        __syncthreads();
#pragma unroll
        for (int i = 0; i < 2; i++) {
            int f = tid + i * 256;
            int c = f >> 4, s4 = (f & 15) * 4;
            sm[(s4 + 0) * 40 + c] = f2b(xreg[i].x);
            sm[(s4 + 1) * 40 + c] = f2b(xreg[i].y);
            sm[(s4 + 2) * 40 + c] = f2b(xreg[i].z);
            sm[(s4 + 3) * 40 + c] = f2b(xreg[i].w);
        }
#pragma unroll
        for (int i = 0; i < 4; i++) {
            int f = tid + i * 256;
            int k = f >> 3, co = (f & 7) * 4;
            ushort4 g4 = {f2b(wgreg[i].x), f2b(wgreg[i].y), f2b(wgreg[i].z), f2b(wgreg[i].w)};
            ushort4 p4 = {f2b(wpreg[i].x), f2b(wpreg[i].y), f2b(wpreg[i].z), f2b(wpreg[i].w)};
            *(ushort4*)&sm[2560 + k * 40 + co] = g4;
            *(ushort4*)&sm[7680 + k * 40 + co] = p4;
        }
        if (c0 + 32 < CCH) {
#pragma unroll
            for (int i = 0; i < 2; i++) {
                int f = tid + i * 256;
                int c = f >> 4, s4 = (f & 15) * 4;
                xreg[i] = *(const float4*)&x[((size_t)n * CCH + c0 + 32 + c) * SSP + s0 + s4];
            }
#pragma unroll
            for (int i = 0; i < 4; i++) {
                int f = tid + i * 256;
                int k = f >> 3, co = (f & 7) * 4;
                wgreg[i] = *(const float4*)&Wg[k * CCH + c0 + 32 + co];
                wpreg[i] = *(const float4*)&Wp[k * CCH + c0 + 32 + co];
            }
        }
        __syncthreads();
        bfrag a = *(const bfrag*)&sm[(16 * wv + l16) * 40 + quad * 8];
#pragma unroll
        for (int kb = 0; kb < 8; kb++) {
            bfrag bgf = *(const bfrag*)&sm[2560 + (16 * kb + l16) * 40 + quad * 8];
            bfrag bpf = *(const bfrag*)&sm[7680 + (16 * kb + l16) * 40 + quad * 8];
            ga[kb] = MFMA16(a, bgf, ga[kb]);
            pa[kb] = MFMA16(a, bpf, pa[kb]);
        }
    }
#pragma unroll
    for (int kb = 0; kb < 8; kb++) {
        int k = l16 + 16 * kb;
        float bgv = bg[k], bpv = bp[k];
        int srow = s0 + 16 * wv + quad * 4;
        ushort4 g4 = {f2b(ga[kb][0] + bgv), f2b(ga[kb][1] + bgv),
                      f2b(ga[kb][2] + bgv), f2b(ga[kb][3] + bgv)};
        *(ushort4*)&G[(size_t)n * KCH * SSP + (size_t)k * SSP + srow] = g4;
#pragma unroll
        for (int r = 0; r < 4; r++)
            P[((size_t)n * SSP + srow + r) * KCH + k] = f2b(pa[kb][r] + bpv);
    }
}

// ---------------------------------------------------------------------------
// K2: fused theta-proj + flash attention + out-proj, all MFMA.
// Round-9 change vs round 8: SCRATCH FIX. Round 8's union{u[4];bfrag} and
// pk[4][2] were demoted to alloca (SROA fails on the union) -> 32 B/lane/iter
// scratch round-trip -> WRITE_SIZE 490 MB, dur 362us. Replaced with 8 named
// scalars + ext-vector build + __builtin_bit_cast (pure SSA, no alloca).
// Structure otherwise identical to round 8:
//  - SWAPPED QK^T: sa = MFMA(K_frag, Q_frag) -> lane holds P[t][q=l16].
//    Softmax fully in-register; 16 __shfl builds the PV A-frag; no PS LDS.
//  - 256-thread blocks, q-tile 64, grid 512 = 2 INDEPENDENT blocks/CU.
//  - LDS 48 KB: QS/YS@0 | ph0 XT@8192 WT@10752 | t-loop KS@8192 GT@16384 |
//    epi WO@8192 (Wo staged in 64-row quarters).
// ---------------------------------------------------------------------------
__global__ __launch_bounds__(256, 2) void attn_fused_kernel(
    const float* __restrict__ x,
    const float* __restrict__ Wt, const float* __restrict__ bt,
    const u16* __restrict__ Pb,   // phi rows bf16 [N,S,K]
    const u16* __restrict__ Gt,   // g bf16 TRANSPOSED [N,K,S]
    const float* __restrict__ Wo, const float* __restrict__ bo,
    float* __restrict__ out)
{
    __shared__ __align__(16) u16 sm[24576];     // 48 KB
    const int tid  = threadIdx.x;
    const int wv   = tid >> 6;                  // 0..3
    const int lane = tid & 63;
    const int quad = lane >> 4, l16 = lane & 15;
    const int bid  = blockIdx.x;
    const int n    = bid & 7;
    const int q0   = (bid >> 3) * 64;
    // 1/sqrt(128) * log2(e): exp(s*scale) == exp2(s*qscale)
    const float qscale = 0.08838834764831845f * 1.4426950408889634f;
    const ffrag zf = {0.f, 0.f, 0.f, 0.f};

    const int XTb = 8192, WTb = 10752, KSb = 8192, GTb = 16384, WOb = 8192;

    const u16* Pbase = Pb + (size_t)n * SSP * KCH;
    const u16* Gbase = Gt + (size_t)n * KCH * SSP;

    // ---- issue first K/G tile loads NOW; they complete during phase 0 ----
    uint4 kreg[4], greg[4];
#pragma unroll
    for (int i = 0; i < 4; i++) {
        int f = tid + i * 256;
        int row = f >> 4, c8 = (f & 15) * 8;
        kreg[i] = *(const uint4*)(Pbase + (size_t)row * KCH + c8);
    }
#pragma unroll
    for (int i = 0; i < 4; i++) {
        int f = tid + i * 256;
        int k = f >> 3, ch = f & 7;
        greg[i] = *(const uint4*)(Gbase + (size_t)k * SSP + ch * 8);
    }

    // ---------------- Phase 0: Qs = (theta(x)+bt)*qscale, bf16 ----------------
    {
        ffrag qa[8];
#pragma unroll
        for (int kb = 0; kb < 8; kb++) qa[kb] = zf;

        for (int c0 = 0; c0 < CCH; c0 += 32) {
#pragma unroll
            for (int i = 0; i < 2; i++) {
                int f = tid + i * 256;
                int c = f >> 4, s4 = (f & 15) * 4;
                float4 xv = *(const float4*)&x[((size_t)n * CCH + c0 + c) * SSP + q0 + s4];
                sm[XTb + (s4 + 0) * 40 + c] = f2b(xv.x);
                sm[XTb + (s4 + 1) * 40 + c] = f2b(xv.y);
                sm[XTb + (s4 + 2) * 40 + c] = f2b(xv.z);
                sm[XTb + (s4 + 3) * 40 + c] = f2b(xv.w);
            }
#pragma unroll
            for (int i = 0; i < 4; i++) {
                int f = tid + i * 256;
                int k = f >> 3, co = (f & 7) * 4;
                float4 wq4 = *(const float4*)&Wt[k * CCH + c0 + co];
                ushort4 q4 = {f2b(wq4.x), f2b(wq4.y), f2b(wq4.z), f2b(wq4.w)};
                *(ushort4*)&sm[WTb + k * 40 + co] = q4;
            }
            __syncthreads();
            bfrag aq = *(const bfrag*)&sm[XTb + (16 * wv + l16) * 40 + quad * 8];
#pragma unroll
            for (int kb = 0; kb < 8; kb++) {
                bfrag bw = *(const bfrag*)&sm[WTb + (16 * kb + l16) * 40 + quad * 8];
                qa[kb] = MFMA16(aq, bw, qa[kb]);
            }
            __syncthreads();
        }
#pragma unroll
        for (int kb = 0; kb < 8; kb++) {
            float btv = bt[l16 + 16 * kb];
#pragma unroll
            for (int r = 0; r < 4; r++) {
                int row = 16 * wv + quad * 4 + r;
                sm[SWZ(row * 128 + l16 + 16 * kb, row)] = f2b((qa[kb][r] + btv) * qscale);
            }
        }
        // QS rows are wave-private; in-wave LDS ordering suffices below.
    }

    // ---- hoist Q B-fragments (own rows, no barrier needed) ----
    bfrag qf[4];
#pragma unroll
    for (int kc = 0; kc < 4; kc++)
        qf[kc] = *(const bfrag*)&sm[SWZ((16 * wv + l16) * 128 + kc * 32 + quad * 8, l16)];

    // ---------------- Phase 1: flash attention over t-tiles ----------------
    ffrag O[8];
#pragma unroll
    for (int kb = 0; kb < 8; kb++) O[kb] = zf;
    float l_lane = 0.f;
    const bool hi32 = lane >= 32;                       // quad 2,3
    const int srcA = (((2 * quad) & 3) << 4) + l16;     // quads {0,2,0,2}
    const int srcB = (((2 * quad + 1) & 3) << 4) + l16; // quads {1,3,1,3}

// PV quarter-tile: builds A-frag (32 t-values) from packed bf16 pairs via
// 8 shfl + 4 cndmask, all SSA (no alloca), then 8 MFMAs against G.
#define PV_STEP(TC, PAL, PAH, PBL, PBH)                                      \
    {                                                                        \
        unsigned w0A = __shfl((PAL), srcA);                                  \
        unsigned w0B = __shfl((PBL), srcA);                                  \
        unsigned w1A = __shfl((PAH), srcA);                                  \
        unsigned w1B = __shfl((PBH), srcA);                                  \
        unsigned w2A = __shfl((PAL), srcB);                                  \
        unsigned w2B = __shfl((PBL), srcB);                                  \
        unsigned w3A = __shfl((PAH), srcB);                                  \
        unsigned w3B = __shfl((PBH), srcB);                                  \
        uint4v apv;                                                          \
        apv.x = hi32 ? w0B : w0A;                                            \
        apv.y = hi32 ? w1B : w1A;                                            \
        apv.z = hi32 ? w2B : w2A;                                            \
        apv.w = hi32 ? w3B : w3A;                                            \
        bfrag apb = __builtin_bit_cast(bfrag, apv);                          \
        _Pragma("unroll")                                                    \
        for (int kb = 0; kb < 8; kb++) {                                     \
            bfrag bg = *(const bfrag*)&sm[GTb + SWZ((16 * kb + l16) * 64 + (TC) * 32 + quad * 8, l16)]; \
            O[kb] = MFMA16(apb, bg, O[kb]);                                  \
        }                                                                    \
    }

    for (int t0 = 0; t0 < SSP; t0 += 64) {
        __syncthreads();                    // previous tile fully consumed
        // ---- commit pipelined tile to LDS (swizzled) ----
#pragma unroll
        for (int i = 0; i < 4; i++) {
            int f = tid + i * 256;
            int row = f >> 4, c8 = (f & 15) * 8;
            *(uint4*)&sm[KSb + SWZ(row * 128 + c8, row)] = kreg[i];
        }
#pragma unroll
        for (int i = 0; i < 4; i++) {
            int f = tid + i * 256;
            int k = f >> 3, ch = f & 7;
            *(uint4*)&sm[GTb + SWZ(k * 64 + ch * 8, k)] = greg[i];
        }
        // ---- prefetch next tile (in flight across the whole compute) ----
        if (t0 + 64 < SSP) {
#pragma unroll
            for (int i = 0; i < 4; i++) {
                int f = tid + i * 256;
                int row = f >> 4, c8 = (f & 15) * 8;
                kreg[i] = *(const uint4*)(Pbase + (size_t)(t0 + 64 + row) * KCH + c8);
            }
#pragma unroll
            for (int i = 0; i < 4; i++) {
                int f = tid + i * 256;
                int k = f >> 3, ch = f & 7;
                greg[i] = *(const uint4*)(Gbase + (size_t)k * SSP + t0 + 64 + ch * 8);
            }
        }
        __syncthreads();                    // staging visible

        // ---- QK^T SWAPPED: sa[tb] lane holds S[t=16tb+quad*4+r][q=l16] ----
        ffrag sa[4];
#pragma unroll
        for (int tb = 0; tb < 4; tb++) sa[tb] = zf;
#pragma unroll
        for (int kc = 0; kc < 4; kc++)
#pragma unroll
            for (int tb = 0; tb < 4; tb++) {
                bfrag bk = *(const bfrag*)&sm[KSb + SWZ((16 * tb + l16) * 128 + kc * 32 + quad * 8, l16)];
                sa[tb] = MFMA16(bk, qf[kc], sa[tb]);
            }

        // ---- softmax numerator in-register: exp2 -> pack bf16 pairs ----
        unsigned pk0l, pk0h, pk1l, pk1h, pk2l, pk2h, pk3l, pk3h;
        {
            float p0, p1, p2, p3;
            p0 = __builtin_amdgcn_exp2f(sa[0][0]); p1 = __builtin_amdgcn_exp2f(sa[0][1]);
            p2 = __builtin_amdgcn_exp2f(sa[0][2]); p3 = __builtin_amdgcn_exp2f(sa[0][3]);
            l_lane += (p0 + p1) + (p2 + p3);
            pk0l = cvt_pk_bf16(p0, p1); pk0h = cvt_pk_bf16(p2, p3);
            p0 = __builtin_amdgcn_exp2f(sa[1][0]); p1 = __builtin_amdgcn_exp2f(sa[1][1]);
            p2 = __builtin_amdgcn_exp2f(sa[1][2]); p3 = __builtin_amdgcn_exp2f(sa[1][3]);
            l_lane += (p0 + p1) + (p2 + p3);
            pk1l = cvt_pk_bf16(p0, p1); pk1h = cvt_pk_bf16(p2, p3);
            p0 = __builtin_amdgcn_exp2f(sa[2][0]); p1 = __builtin_amdgcn_exp2f(sa[2][1]);
            p2 = __builtin_amdgcn_exp2f(sa[2][2]); p3 = __builtin_amdgcn_exp2f(sa[2][3]);
            l_lane += (p0 + p1) + (p2 + p3);
            pk2l = cvt_pk_bf16(p0, p1); pk2h = cvt_pk_bf16(p2, p3);
            p0 = __builtin_amdgcn_exp2f(sa[3][0]); p1 = __builtin_amdgcn_exp2f(sa[3][1]);
            p2 = __builtin_amdgcn_exp2f(sa[3][2]); p3 = __builtin_amdgcn_exp2f(sa[3][3]);
            l_lane += (p0 + p1) + (p2 + p3);
            pk3l = cvt_pk_bf16(p0, p1); pk3h = cvt_pk_bf16(p2, p3);
        }

        // ---- PV: O += P * G (A-frags rebuilt in-register, no LDS) ----
        PV_STEP(0, pk0l, pk0h, pk1l, pk1h)
        PV_STEP(1, pk2l, pk2h, pk3l, pk3h)
    }
#undef PV_STEP

    // ---------------- Phase 2: reduce l; y -> YS; out = x + Wo*y + bo ----
    {
        float rs = l_lane;                  // partial for q=l16 over own quad's t
        rs += __shfl_xor(rs, 16);
        rs += __shfl_xor(rs, 32);
        float linv = 1.0f / rs;             // lane holds 1/L[q_local = l16]
        float lr0 = __shfl(linv, quad * 4 + 0);
        float lr1 = __shfl(linv, quad * 4 + 1);
        float lr2 = __shfl(linv, quad * 4 + 2);
        float lr3 = __shfl(linv, quad * 4 + 3);
#pragma unroll
        for (int kb = 0; kb < 8; kb++) {
            int rowb = 16 * wv + quad * 4;
            sm[SWZ((rowb + 0) * 128 + l16 + 16 * kb, rowb + 0)] = f2b(O[kb][0] * lr0);
            sm[SWZ((rowb + 1) * 128 + l16 + 16 * kb, rowb + 1)] = f2b(O[kb][1] * lr1);
            sm[SWZ((rowb + 2) * 128 + l16 + 16 * kb, rowb + 2)] = f2b(O[kb][2] * lr2);
            sm[SWZ((rowb + 3) * 128 + l16 + 16 * kb, rowb + 3)] = f2b(O[kb][3] * lr3);
        }
    }

#pragma unroll
    for (int qtr = 0; qtr < 4; qtr++) {
        __syncthreads();    // KS/GT (or prev WO) reads done before overwrite
        // stage Wo rows [qtr*64, qtr*64+64) bf16, swizzled [64][128]
#pragma unroll
        for (int i = 0; i < 8; i++) {
            int f = tid + i * 256;
            int c = f >> 5, ko = (f & 31) * 4;
            float4 w = *(const float4*)&Wo[(size_t)(qtr * 64 + c) * KCH + ko];
            ushort4 w4 = {f2b(w.x), f2b(w.y), f2b(w.z), f2b(w.w)};
            *(ushort4*)&sm[WOb + SWZ(c * 128 + ko, c)] = w4;
        }
        __syncthreads();

        ffrag zc[4];
#pragma unroll
        for (int cb = 0; cb < 4; cb++) zc[cb] = zf;
#pragma unroll
        for (int kc = 0; kc < 4; kc++) {
            bfrag ay = *(const bfrag*)&sm[SWZ((16 * wv + l16) * 128 + kc * 32 + quad * 8, l16)];
#pragma unroll
            for (int cb = 0; cb < 4; cb++) {
                bfrag bw = *(const bfrag*)&sm[WOb + SWZ((16 * cb + l16) * 128 + kc * 32 + quad * 8, l16)];
                zc[cb] = MFMA16(ay, bw, zc[cb]);
            }
        }
#pragma unroll
        for (int cb = 0; cb < 4; cb++) {
            int c = qtr * 64 + 16 * cb + l16;
            float bc = bo[c];
            size_t base = ((size_t)n * CCH + c) * SSP + q0 + 16 * wv + quad * 4;
            float4 xv = *(const float4*)&x[base];
            float4 ov;
            ov.x = xv.x + zc[cb][0] + bc;
            ov.y = xv.y + zc[cb][1] + bc;
            ov.z = xv.z + zc[cb][2] + bc;
            ov.w = xv.w + zc[cb][3] + bc;
            *(float4*)&out[base] = ov;
        }
    }
}

// ---------------------------------------------------------------------------
extern "C" void kernel_launch(void* const* d_in, const int* in_sizes, int n_in,
                              void* d_out, int out_size, void* d_ws, size_t ws_size,
                              hipStream_t stream) {
    const float* x  = (const float*)d_in[0];
    const float* Wg = (const float*)d_in[1];
    const float* bg = (const float*)d_in[2];
    const float* Wt = (const float*)d_in[3];
    const float* bt = (const float*)d_in[4];
    const float* Wp = (const float*)d_in[5];
    const float* bp = (const float*)d_in[6];
    const float* Wo = (const float*)d_in[7];
    const float* bo = (const float*)d_in[8];
    float* out = (float*)d_out;

    // ws: 16 MB total (verified-safe): G^T bf16 8MB + P bf16 8MB.
    u16* G = (u16*)d_ws;                       // [N,K,S] transposed
    u16* P = G + (size_t)NB * SSP * KCH;       // [N,S,K]

    proj_gp_kernel<<<dim3(NB * SSP / 64), 256, 0, stream>>>(x, Wg, bg, Wp, bp, G, P);
    attn_fused_kernel<<<dim3(NB * SSP / 64), 256, 0, stream>>>(x, Wt, bt, P, G, Wo, bo, out);
}